// Round 12
// baseline (294.468 us; speedup 1.0000x reference)
//
#include <hip/hip_runtime.h>
#include <stdint.h>

#define S_LEN 256
#define DIM   128
#define EPSL  1e-5f

typedef __bf16 bf16x8 __attribute__((ext_vector_type(8)));
typedef float  f32x4  __attribute__((ext_vector_type(4)));

__device__ __forceinline__ unsigned short f2bf_bits(float f) {
  union { float f; unsigned int u; } v; v.f = f;
  unsigned int r = v.u + 0x7fffu + ((v.u >> 16) & 1u);   // RTNE (init paths)
  return (unsigned short)(r >> 16);
}
__device__ __forceinline__ float bf2f_bits(unsigned short b) {
  union { float f; unsigned int u; } v; v.u = ((unsigned int)b) << 16; return v.f;
}
// Hot-path bf16 round-half-up: 2 VALU ops.
__device__ __forceinline__ unsigned f2bf_rhu(float f) {
  return (__float_as_uint(f) + 0x8000u) >> 16;
}
// Pack two floats -> (bf16 lo, bf16 hi) in one u32: 2 adds + 1 v_perm.
__device__ __forceinline__ unsigned pack_rhu(float lo, float hi) {
  return __builtin_amdgcn_perm(__float_as_uint(hi) + 0x8000u,
                               __float_as_uint(lo) + 0x8000u, 0x07060302u);
}
// tanh(x) = 1 - 2/(e^{2x}+1): ~1e-6 rel err, exact at +-inf.
__device__ __forceinline__ float tanh_fast(float x) {
  float e = __expf(2.f * x);
  return 1.f - 2.f * __builtin_amdgcn_rcpf(e + 1.f);
}

// VALU cross-lane via DPP rotation; 16-lane reduce visible on all lanes.
template<int CTRL>
__device__ __forceinline__ float dpp_rot_add(float v) {
  int r = __builtin_amdgcn_update_dpp(0, __float_as_int(v), CTRL, 0xF, 0xF, true);
  return v + __int_as_float(r);
}
template<int CTRL>
__device__ __forceinline__ float dpp_rot_max(float v) {
  int r = __builtin_amdgcn_update_dpp(0, __float_as_int(v), CTRL, 0xF, 0xF, true);
  return fmaxf(v, __int_as_float(r));
}
__device__ __forceinline__ float dpp_sum16(float v) {
  v = dpp_rot_add<0x124>(v); v = dpp_rot_add<0x128>(v);
  v = dpp_rot_add<0x39>(v);  v = dpp_rot_add<0x4E>(v);
  return v;
}
__device__ __forceinline__ float dpp_max16(float v) {
  v = dpp_rot_max<0x124>(v); v = dpp_rot_max<0x128>(v);
  v = dpp_rot_max<0x39>(v);  v = dpp_rot_max<0x4E>(v);
  return v;
}
template<int CTRL>
__device__ __forceinline__ void red_level7(float& s, float& sq, float* d) {
  s  = dpp_rot_add<CTRL>(s);
  sq = dpp_rot_add<CTRL>(sq);
#pragma unroll
  for (int j = 0; j < 5; j++) d[j] = dpp_rot_add<CTRL>(d[j]);
}
template<int JJ>
__device__ __forceinline__ float bcast16(float v) {
  int r = __builtin_amdgcn_ds_swizzle(__float_as_int(v), (JJ << 5) | 0x10);
  return __int_as_float(r);
}

union Frag8 { unsigned short us[8]; bf16x8 v; int4 i4; };

// ===================== Kernel 1: serial recurrence only =====================
// (R11 rnn_core, unchanged -- measured 129 us.)
__global__ __launch_bounds__(512, 2)
void rnn_core(const int* __restrict__ x, const float* __restrict__ emb,
              const float* __restrict__ Wih1, const float* __restrict__ bih1,
              const float* __restrict__ Whh1, const float* __restrict__ bhh1,
              unsigned short* __restrict__ hout)
{
  __shared__ __align__(16) unsigned short h_bf[2][16 * 128];   // 8 KB
  __shared__ __align__(16) unsigned short e_bf[2][16 * 128];   // 8 KB
  __shared__ int x_tile[16 * 256];                             // 16 KB

  const int tid  = threadIdx.x;
  const int wave = tid >> 6;
  const int lane = tid & 63;
  const int r0   = blockIdx.x * 16;
  const int l15  = lane & 15;
  const int q    = lane >> 4;

  for (int i = tid; i < 16 * 256; i += 512)
    x_tile[i] = x[(size_t)(r0 + (i >> 8)) * S_LEN + (i & 255)];
  for (int i = tid; i < 16 * 128; i += 512) h_bf[1][i] = 0;   // h_{-1} = 0

  const int n1 = wave * 16 + l15;
  const float bias1v = bih1[n1] + bhh1[n1];
  bf16x8 wh[4], wih[4];
#pragma unroll
  for (int kt = 0; kt < 4; kt++) {
    int k0 = kt * 32 + q * 8;
    Frag8 fh, fa;
#pragma unroll
    for (int j = 0; j < 8; j++) {
      fh.us[j] = f2bf_bits(Whh1[n1 * DIM + k0 + j]);
      fa.us[j] = f2bf_bits(Wih1[n1 * DIM + k0 + j]);
    }
    wh[kt] = fh.v; wih[kt] = fa.v;
  }

  const bool stage_role = (wave >= 4);
  float pf[2][8];
  const int gm   = (wave & 3) * 4 + q;   // staging row (waves 4-7)
  const int goct = l15;
  const int gdst = gm * 128 + ((goct ^ gm) & 15) * 8;
  __syncthreads();

  if (stage_role) {                      // stage e[0],e[1]; preload pf=e[2],e[3]
    float ta[8], tb[8];
    { int xid = x_tile[gm * 256 + 0];
      const float* pe = emb + (size_t)xid * DIM + goct * 8;
#pragma unroll
      for (int j = 0; j < 8; j++) ta[j] = pe[j]; }
    { int xid = x_tile[gm * 256 + 1];
      const float* pe = emb + (size_t)xid * DIM + goct * 8;
#pragma unroll
      for (int j = 0; j < 8; j++) tb[j] = pe[j]; }
    { int xid = x_tile[gm * 256 + 2];
      const float* pe = emb + (size_t)xid * DIM + goct * 8;
#pragma unroll
      for (int j = 0; j < 8; j++) pf[0][j] = pe[j]; }
    { int xid = x_tile[gm * 256 + 3];
      const float* pe = emb + (size_t)xid * DIM + goct * 8;
#pragma unroll
      for (int j = 0; j < 8; j++) pf[1][j] = pe[j]; }
    Frag8 pa, pb;
#pragma unroll
    for (int j = 0; j < 8; j++) { pa.us[j] = f2bf_bits(ta[j]); pb.us[j] = f2bf_bits(tb[j]); }
    *(int4*)&e_bf[0][gdst] = pa.i4;
    *(int4*)&e_bf[1][gdst] = pb.i4;
  }
  __syncthreads();

  // xpacc = e[0]@Wih^T + bias for this wave's n-tile (register handoff)
  f32x4 xpacc = {bias1v, bias1v, bias1v, bias1v};
#pragma unroll
  for (int kt = 0; kt < 4; kt++) {
    int sw = (((kt * 4 + q) ^ l15) & 15) * 8;
    bf16x8 ae = *(const bf16x8*)&e_bf[0][l15 * 128 + sw];
    xpacc = __builtin_amdgcn_mfma_f32_16x16x32_bf16(ae, wih[kt], xpacc, 0, 0, 0);
  }
  asm volatile("s_waitcnt lgkmcnt(0)\n\ts_barrier" ::: "memory");

#pragma unroll 2
  for (int t = 0; t < S_LEN; t++) {
    // ---- serial core: acc seeded with xpacc, ONE depth-4 chain ----
    f32x4 acc = xpacc;
    {
      const int rb = (t + 1) & 1;        // h_{t-1}
#pragma unroll
      for (int kt = 0; kt < 4; kt++) {
        int sw = (((kt * 4 + q) ^ l15) & 15) * 8;
        bf16x8 ahf = *(const bf16x8*)&h_bf[rb][l15 * 128 + sw];
        acc = __builtin_amdgcn_mfma_f32_16x16x32_bf16(ahf, wh[kt], acc, 0, 0, 0);
      }
      const int wb = t & 1;
      const int oct = n1 >> 3;
#pragma unroll
      for (int r = 0; r < 4; r++) {      // D-layout: row = q*4 + r, col = l15
        int row = q * 4 + r;
        unsigned short us = (unsigned short)f2bf_rhu(tanh_fast(acc[r]));
        h_bf[wb][row * 128 + ((oct ^ row) & 15) * 8 + (n1 & 7)] = us;
        // off-chain h stream-out for rnn_tail (never waited in-loop)
        hout[((size_t)(r0 + row) * S_LEN + t) * DIM + n1] = us;
      }
    }

    if (t + 1 < S_LEN) {                 // e_{t+1}@Wih into regs (off-chain)
      f32x4 a = {bias1v, bias1v, bias1v, bias1v};
#pragma unroll
      for (int kt = 0; kt < 4; kt++) {
        int sw = (((kt * 4 + q) ^ l15) & 15) * 8;
        bf16x8 ae = *(const bf16x8*)&e_bf[(t + 1) & 1][l15 * 128 + sw];
        a = __builtin_amdgcn_mfma_f32_16x16x32_bf16(ae, wih[kt], a, 0, 0, 0);
      }
      xpacc = a;
    }

    if (stage_role) {
      if (t + 2 < S_LEN) {               // stage e[t+2] (gathered at t-2)
        int4 pk;
        pk.x = pack_rhu(pf[t & 1][0], pf[t & 1][1]);
        pk.y = pack_rhu(pf[t & 1][2], pf[t & 1][3]);
        pk.z = pack_rhu(pf[t & 1][4], pf[t & 1][5]);
        pk.w = pack_rhu(pf[t & 1][6], pf[t & 1][7]);
        *(int4*)&e_bf[t & 1][gdst] = pk;
      }
      if (t + 4 < S_LEN) {               // issue gather e[t+4] (2-step cover)
        int xid = x_tile[gm * 256 + t + 4];
        const float* pe = emb + (size_t)xid * DIM + goct * 8;
#pragma unroll
        for (int j = 0; j < 8; j++) pf[t & 1][j] = pe[j];
      }
    }
    // Raw barrier: drain LDS only; gathers and h-stores stay in flight.
    asm volatile("s_waitcnt lgkmcnt(0)\n\ts_barrier" ::: "memory");
  }
}

// ===================== Kernel 2: layer-2 tail, two-phase ====================
// 256 blocks x 4 waves; wave owns batch row b.
// Phase A (parallel): LN1+proj for all 256 t in 64 group-parallel iterations,
// p[t][5] -> per-wave LDS. Phase B (serial): 5-dim RNN2/LN2/pool entirely in
// scalar registers -- zero cross-lane ops on the serial chain.
__global__ __launch_bounds__(256, 2)
void rnn_tail(const unsigned short* __restrict__ hall,
              const float* __restrict__ g1,  const float* __restrict__ be1,
              const float* __restrict__ Wih2, const float* __restrict__ bih2,
              const float* __restrict__ Whh2, const float* __restrict__ bhh2,
              const float* __restrict__ g2,  const float* __restrict__ be2,
              float* __restrict__ out)
{
  __shared__ __align__(16) float p_lds[4][S_LEN][8];   // 32 KB
  const int tid  = threadIdx.x;
  const int wave = tid >> 6;
  const int lane = tid & 63;
  const int l15  = lane & 15;
  const int q    = lane >> 4;
  const int b    = blockIdx.x * 4 + wave;

  // LN1 fold constants (this lane's 8 channels, plain row-major)
  float w2g[5][8], Gs[5], Bs[5];
#pragma unroll
  for (int j = 0; j < 8; j++) {
    int c = l15 * 8 + j;
    float gc = g1[c];
#pragma unroll
    for (int jj = 0; jj < 5; jj++) w2g[jj][j] = Wih2[jj * DIM + c] * gc;
  }
#pragma unroll
  for (int jj = 0; jj < 5; jj++) { Gs[jj] = 0.f; Bs[jj] = 0.f; }
  for (int c = 0; c < DIM; c++) {
    float gc = g1[c], bc = be1[c];
#pragma unroll
    for (int jj = 0; jj < 5; jj++) {
      float w = Wih2[jj * DIM + c];
      Gs[jj] += w * gc; Bs[jj] += w * bc;
    }
  }
  // full RNN2/LN2 constants in every lane (phase B is cross-lane-free)
  float t2v[5], g2v[5], be2v[5], whh2v[5][5];
#pragma unroll
  for (int jj = 0; jj < 5; jj++) {
    t2v[jj] = bih2[jj] + bhh2[jj];
    g2v[jj] = g2[jj]; be2v[jj] = be2[jj];
#pragma unroll
    for (int k = 0; k < 5; k++) whh2v[jj][k] = Whh2[jj * 5 + k];
  }

  const unsigned short* hb = hall + (size_t)b * S_LEN * DIM;
  uint4 hpre = *(const uint4*)(hb + (size_t)q * DIM + l15 * 8);

  // ---- Phase A: group q handles t = t0 + q ----
  for (int t0 = 0; t0 < S_LEN; t0 += 4) {
    uint4 cur = hpre;
    if (t0 + 4 < S_LEN)                  // prefetch next chunk (off-chain)
      hpre = *(const uint4*)(hb + (size_t)(t0 + 4 + q) * DIM + l15 * 8);
    float hv[8];
    hv[0] = __uint_as_float(cur.x << 16); hv[1] = __uint_as_float(cur.x & 0xffff0000u);
    hv[2] = __uint_as_float(cur.y << 16); hv[3] = __uint_as_float(cur.y & 0xffff0000u);
    hv[4] = __uint_as_float(cur.z << 16); hv[5] = __uint_as_float(cur.z & 0xffff0000u);
    hv[6] = __uint_as_float(cur.w << 16); hv[7] = __uint_as_float(cur.w & 0xffff0000u);
    float s = 0.f, sq = 0.f, d[5] = {0, 0, 0, 0, 0};
#pragma unroll
    for (int j = 0; j < 8; j++) {
      float v = hv[j];
      s += v; sq += v * v;
#pragma unroll
      for (int jj = 0; jj < 5; jj++) d[jj] = fmaf(w2g[jj][j], v, d[jj]);
    }
    red_level7<0x124>(s, sq, d);
    red_level7<0x128>(s, sq, d);
    red_level7<0x39>(s, sq, d);
    red_level7<0x4E>(s, sq, d);
    float mean = s * (1.f / 128.f);
    float var  = sq * (1.f / 128.f) - mean * mean;
    float rstd = rsqrtf(var + EPSL);
    float p[5];
#pragma unroll
    for (int jj = 0; jj < 5; jj++)
      p[jj] = rstd * (d[jj] - mean * Gs[jj]) + Bs[jj];
    float psel = (l15 == 0) ? p[0] : (l15 == 1) ? p[1] :
                 (l15 == 2) ? p[2] : (l15 == 3) ? p[3] : p[4];
    if (l15 < 5) p_lds[wave][t0 + q][l15] = psel;
  }
  __syncthreads();                       // phase A writes -> phase B reads

  // ---- Phase B: pure-register serial scan, no cross-lane ----
  float h2[5] = {0, 0, 0, 0, 0}, pool[5] = {0, 0, 0, 0, 0};
#pragma unroll 4
  for (int t = 0; t < S_LEN; t++) {
    float4 pq = *(const float4*)&p_lds[wave][t][0];    // broadcast reads
    float  p4 = p_lds[wave][t][4];
    float pv[5] = {pq.x, pq.y, pq.z, pq.w, p4};
    float xn[5];
#pragma unroll
    for (int j = 0; j < 5; j++) {
      float a = pv[j] + t2v[j];
#pragma unroll
      for (int k = 0; k < 5; k++) a = fmaf(whh2v[j][k], h2[k], a);
      xn[j] = tanh_fast(a);
    }
    float m2 = (xn[0] + xn[1] + xn[2] + xn[3] + xn[4]) * 0.2f;
    float v2 = 0.f;
#pragma unroll
    for (int j = 0; j < 5; j++) { float dd = xn[j] - m2; v2 += dd * dd; }
    v2 *= 0.2f;
    float r2 = rsqrtf(v2 + EPSL);
#pragma unroll
    for (int j = 0; j < 5; j++) {
      pool[j] += (xn[j] - m2) * r2 * g2v[j] + be2v[j];
      h2[j] = xn[j];
    }
  }

  if (lane == 0) {                       // softmax, scalar in-register
    float lg[5], mx = -1e30f;
#pragma unroll
    for (int j = 0; j < 5; j++) { lg[j] = pool[j] * (1.f / 256.f); mx = fmaxf(mx, lg[j]); }
    float sm = 0.f, ex[5];
#pragma unroll
    for (int j = 0; j < 5; j++) { ex[j] = __expf(lg[j] - mx); sm += ex[j]; }
    float inv = 1.f / sm;
#pragma unroll
    for (int j = 0; j < 5; j++) out[(size_t)b * 5 + j] = ex[j] * inv;
  }
}

// ===================== Fallback: R9 fused single kernel =====================
__global__ __launch_bounds__(512, 2)
void rnn_fused_fb(const int* __restrict__ x, const float* __restrict__ emb,
                  const float* __restrict__ Wih1, const float* __restrict__ bih1,
                  const float* __restrict__ Whh1, const float* __restrict__ bhh1,
                  const float* __restrict__ g1, const float* __restrict__ be1,
                  const float* __restrict__ Wih2, const float* __restrict__ bih2,
                  const float* __restrict__ Whh2, const float* __restrict__ bhh2,
                  const float* __restrict__ g2, const float* __restrict__ be2,
                  float* __restrict__ out)
{
  __shared__ __align__(16) unsigned short h_bf[2][16 * 128];
  __shared__ __align__(16) unsigned short e_bf[2][16 * 128];
  __shared__ int x_tile[16 * 256];

  const int tid  = threadIdx.x;
  const int wave = tid >> 6;
  const int lane = tid & 63;
  const int r0   = blockIdx.x * 16;
  const int l15  = lane & 15;
  const int q    = lane >> 4;

  for (int i = tid; i < 16 * 256; i += 512)
    x_tile[i] = x[(size_t)(r0 + (i >> 8)) * S_LEN + (i & 255)];
  for (int i = tid; i < 16 * 128; i += 512) h_bf[1][i] = 0;

  const int n1 = wave * 16 + l15;
  const float bias1v = bih1[n1] + bhh1[n1];
  bf16x8 wh[4], wih[4];
#pragma unroll
  for (int kt = 0; kt < 4; kt++) {
    int k0 = kt * 32 + q * 8;
    Frag8 fh, fa;
#pragma unroll
    for (int j = 0; j < 8; j++) {
      fh.us[j] = f2bf_bits(Whh1[n1 * DIM + k0 + j]);
      fa.us[j] = f2bf_bits(Wih1[n1 * DIM + k0 + j]);
    }
    wh[kt] = fh.v; wih[kt] = fa.v;
  }

  const bool ln_role = (wave < 4);
  float w2g[5][8], Gs[5], Bs[5], wrow[5];
  float t2_l = 0.f, g2_l = 0.f, be2_l = 0.f, validf = 0.f;
  float h2rep[5], pool_l = 0.f;
  int myrow = 0;
  float pf[2][8];
  const int gm   = (wave & 3) * 4 + q;
  const int goct = l15;
  const int gdst = gm * 128 + ((goct ^ gm) & 15) * 8;

  if (ln_role) {
    myrow = wave * 4 + q;
    int coct = (l15 ^ myrow) & 15;
#pragma unroll
    for (int j = 0; j < 8; j++) {
      int c = coct * 8 + j;
      float gc = g1[c];
#pragma unroll
      for (int jj = 0; jj < 5; jj++) w2g[jj][j] = Wih2[jj * DIM + c] * gc;
    }
#pragma unroll
    for (int jj = 0; jj < 5; jj++) { Gs[jj] = 0.f; Bs[jj] = 0.f; }
    for (int c = 0; c < DIM; c++) {
      float gc = g1[c], bc = be1[c];
#pragma unroll
      for (int jj = 0; jj < 5; jj++) {
        float w = Wih2[jj * DIM + c];
        Gs[jj] += w * gc; Bs[jj] += w * bc;
      }
    }
    validf = (l15 < 5) ? 1.f : 0.f;
    if (l15 < 5) {
      t2_l = bih2[l15] + bhh2[l15];
      g2_l = g2[l15]; be2_l = be2[l15];
#pragma unroll
      for (int jj = 0; jj < 5; jj++) wrow[jj] = Whh2[l15 * 5 + jj];
    } else {
#pragma unroll
      for (int jj = 0; jj < 5; jj++) wrow[jj] = 0.f;
    }
#pragma unroll
    for (int jj = 0; jj < 5; jj++) h2rep[jj] = 0.f;
  }
  __syncthreads();

  if (!ln_role) {
    float ta[8], tb[8];
    { int xid = x_tile[gm * 256 + 0];
      const float* pe = emb + (size_t)xid * DIM + goct * 8;
#pragma unroll
      for (int j = 0; j < 8; j++) ta[j] = pe[j]; }
    { int xid = x_tile[gm * 256 + 1];
      const float* pe = emb + (size_t)xid * DIM + goct * 8;
#pragma unroll
      for (int j = 0; j < 8; j++) tb[j] = pe[j]; }
    { int xid = x_tile[gm * 256 + 2];
      const float* pe = emb + (size_t)xid * DIM + goct * 8;
#pragma unroll
      for (int j = 0; j < 8; j++) pf[0][j] = pe[j]; }
    { int xid = x_tile[gm * 256 + 3];
      const float* pe = emb + (size_t)xid * DIM + goct * 8;
#pragma unroll
      for (int j = 0; j < 8; j++) pf[1][j] = pe[j]; }
    Frag8 pa, pb;
#pragma unroll
    for (int j = 0; j < 8; j++) { pa.us[j] = f2bf_bits(ta[j]); pb.us[j] = f2bf_bits(tb[j]); }
    *(int4*)&e_bf[0][gdst] = pa.i4;
    *(int4*)&e_bf[1][gdst] = pb.i4;
  }
  __syncthreads();

  f32x4 xpacc = {bias1v, bias1v, bias1v, bias1v};
#pragma unroll
  for (int kt = 0; kt < 4; kt++) {
    int sw = (((kt * 4 + q) ^ l15) & 15) * 8;
    bf16x8 ae = *(const bf16x8*)&e_bf[0][l15 * 128 + sw];
    xpacc = __builtin_amdgcn_mfma_f32_16x16x32_bf16(ae, wih[kt], xpacc, 0, 0, 0);
  }
  asm volatile("s_waitcnt lgkmcnt(0)\n\ts_barrier" ::: "memory");

#pragma unroll 2
  for (int t = 0; t <= S_LEN; t++) {
    f32x4 acc = xpacc;
    if (t < S_LEN) {
      const int rb = (t + 1) & 1;
#pragma unroll
      for (int kt = 0; kt < 4; kt++) {
        int sw = (((kt * 4 + q) ^ l15) & 15) * 8;
        bf16x8 ahf = *(const bf16x8*)&h_bf[rb][l15 * 128 + sw];
        acc = __builtin_amdgcn_mfma_f32_16x16x32_bf16(ahf, wh[kt], acc, 0, 0, 0);
      }
      const int wb = t & 1;
      const int oct = n1 >> 3;
#pragma unroll
      for (int r = 0; r < 4; r++) {
        int row = q * 4 + r;
        h_bf[wb][row * 128 + ((oct ^ row) & 15) * 8 + (n1 & 7)] =
            (unsigned short)f2bf_rhu(tanh_fast(acc[r]));
      }
    }
    if (t + 1 < S_LEN) {
      f32x4 a = {bias1v, bias1v, bias1v, bias1v};
#pragma unroll
      for (int kt = 0; kt < 4; kt++) {
        int sw = (((kt * 4 + q) ^ l15) & 15) * 8;
        bf16x8 ae = *(const bf16x8*)&e_bf[(t + 1) & 1][l15 * 128 + sw];
        a = __builtin_amdgcn_mfma_f32_16x16x32_bf16(ae, wih[kt], a, 0, 0, 0);
      }
      xpacc = a;
    }
    if (!ln_role) {
      if (t + 2 < S_LEN) {
        int4 pk;
        pk.x = pack_rhu(pf[t & 1][0], pf[t & 1][1]);
        pk.y = pack_rhu(pf[t & 1][2], pf[t & 1][3]);
        pk.z = pack_rhu(pf[t & 1][4], pf[t & 1][5]);
        pk.w = pack_rhu(pf[t & 1][6], pf[t & 1][7]);
        *(int4*)&e_bf[t & 1][gdst] = pk;
      }
      if (t + 4 < S_LEN) {
        int xid = x_tile[gm * 256 + t + 4];
        const float* pe = emb + (size_t)xid * DIM + goct * 8;
#pragma unroll
        for (int j = 0; j < 8; j++) pf[t & 1][j] = pe[j];
      }
    } else if (t >= 1) {
      const int hb = (t - 1) & 1;
      Frag8 hr;
      hr.i4 = *(const int4*)&h_bf[hb][myrow * 128 + l15 * 8];
      float s = 0.f, sq = 0.f, d[5] = {0, 0, 0, 0, 0};
#pragma unroll
      for (int j = 0; j < 8; j++) {
        float v = bf2f_bits(hr.us[j]);
        s += v; sq += v * v;
#pragma unroll
        for (int jj = 0; jj < 5; jj++) d[jj] = fmaf(w2g[jj][j], v, d[jj]);
      }
      red_level7<0x124>(s, sq, d);
      red_level7<0x128>(s, sq, d);
      red_level7<0x39>(s, sq, d);
      red_level7<0x4E>(s, sq, d);
      float mean = s * (1.f / 128.f);
      float var  = sq * (1.f / 128.f) - mean * mean;
      float rstd = rsqrtf(var + EPSL);
      float p[5];
#pragma unroll
      for (int jj = 0; jj < 5; jj++)
        p[jj] = rstd * (d[jj] - mean * Gs[jj]) + Bs[jj];
      float psel = (l15 == 0) ? p[0] : (l15 == 1) ? p[1] :
                   (l15 == 2) ? p[2] : (l15 == 3) ? p[3] : p[4];
      float a = psel + t2_l;
#pragma unroll
      for (int jj = 0; jj < 5; jj++) a = fmaf(wrow[jj], h2rep[jj], a);
      float xn = tanh_fast(a);
      float s2 = dpp_sum16(xn * validf) * 0.2f;
      float dd = xn - s2;
      float v2 = dpp_sum16(dd * dd * validf) * 0.2f;
      float r2 = rsqrtf(v2 + EPSL);
      pool_l += dd * r2 * g2_l + be2_l;
      h2rep[0] = bcast16<0>(xn); h2rep[1] = bcast16<1>(xn);
      h2rep[2] = bcast16<2>(xn); h2rep[3] = bcast16<3>(xn);
      h2rep[4] = bcast16<4>(xn);
    }
    asm volatile("s_waitcnt lgkmcnt(0)\n\ts_barrier" ::: "memory");
  }

  if (ln_role) {
    float lg = pool_l * (1.f / 256.f);
    float mx = dpp_max16((l15 < 5) ? lg : -3.0e38f);
    float e  = (l15 < 5) ? __expf(lg - mx) : 0.f;
    float sm = dpp_sum16(e);
    if (l15 < 5) out[(size_t)(r0 + myrow) * 5 + l15] = e / sm;
  }
}

extern "C" void kernel_launch(void* const* d_in, const int* in_sizes, int n_in,
                              void* d_out, int out_size, void* d_ws, size_t ws_size,
                              hipStream_t stream) {
  (void)in_sizes; (void)n_in; (void)out_size;
  const int*   x    = (const int*)  d_in[0];
  const float* emb  = (const float*)d_in[1];
  const float* Wih1 = (const float*)d_in[2];
  const float* bih1 = (const float*)d_in[3];
  const float* Whh1 = (const float*)d_in[4];
  const float* bhh1 = (const float*)d_in[5];
  const float* g1   = (const float*)d_in[6];
  const float* be1  = (const float*)d_in[7];
  const float* Wih2 = (const float*)d_in[8];
  const float* bih2 = (const float*)d_in[9];
  const float* Whh2 = (const float*)d_in[10];
  const float* bhh2 = (const float*)d_in[11];
  const float* g2   = (const float*)d_in[12];
  const float* be2  = (const float*)d_in[13];
  float* out = (float*)d_out;

  const size_t HBYTES = (size_t)1024 * S_LEN * DIM * 2;   // 64 MiB bf16 h-buffer
  if (ws_size >= HBYTES) {
    unsigned short* hws = (unsigned short*)d_ws;
    rnn_core<<<dim3(64), dim3(512), 0, stream>>>(x, emb, Wih1, bih1, Whh1, bhh1, hws);
    rnn_tail<<<dim3(256), dim3(256), 0, stream>>>(hws, g1, be1, Wih2, bih2,
                                                  Whh2, bhh2, g2, be2, out);
  } else {
    rnn_fused_fb<<<dim3(64), dim3(512), 0, stream>>>(
        x, emb, Wih1, bih1, Whh1, bhh1, g1, be1,
        Wih2, bih2, Whh2, bhh2, g2, be2, out);
  }
}

// Round 13
// 255.500 us; speedup vs baseline: 1.1525x; 1.1525x over previous
//
#include <hip/hip_runtime.h>
#include <stdint.h>

#define S_LEN 256
#define DIM   128
#define EPSL  1e-5f

typedef __bf16 bf16x8 __attribute__((ext_vector_type(8)));
typedef float  f32x4  __attribute__((ext_vector_type(4)));

__device__ __forceinline__ unsigned short f2bf_bits(float f) {
  union { float f; unsigned int u; } v; v.f = f;
  unsigned int r = v.u + 0x7fffu + ((v.u >> 16) & 1u);   // RTNE (init paths)
  return (unsigned short)(r >> 16);
}
__device__ __forceinline__ float bf2f_bits(unsigned short b) {
  union { float f; unsigned int u; } v; v.u = ((unsigned int)b) << 16; return v.f;
}
__device__ __forceinline__ unsigned f2bf_rhu(float f) {
  return (__float_as_uint(f) + 0x8000u) >> 16;
}
__device__ __forceinline__ unsigned pack_rhu(float lo, float hi) {
  return __builtin_amdgcn_perm(__float_as_uint(hi) + 0x8000u,
                               __float_as_uint(lo) + 0x8000u, 0x07060302u);
}
// tanh(x) = 1 - 2/(e^{2x}+1): ~1e-6 rel err, exact at +-inf.
__device__ __forceinline__ float tanh_fast(float x) {
  float e = __expf(2.f * x);
  return 1.f - 2.f * __builtin_amdgcn_rcpf(e + 1.f);
}

template<int CTRL>
__device__ __forceinline__ float dpp_rot_add(float v) {
  int r = __builtin_amdgcn_update_dpp(0, __float_as_int(v), CTRL, 0xF, 0xF, true);
  return v + __int_as_float(r);
}
template<int CTRL>
__device__ __forceinline__ float dpp_rot_max(float v) {
  int r = __builtin_amdgcn_update_dpp(0, __float_as_int(v), CTRL, 0xF, 0xF, true);
  return fmaxf(v, __int_as_float(r));
}
__device__ __forceinline__ float dpp_sum16(float v) {
  v = dpp_rot_add<0x124>(v); v = dpp_rot_add<0x128>(v);
  v = dpp_rot_add<0x39>(v);  v = dpp_rot_add<0x4E>(v);
  return v;
}
__device__ __forceinline__ float dpp_max16(float v) {
  v = dpp_rot_max<0x124>(v); v = dpp_rot_max<0x128>(v);
  v = dpp_rot_max<0x39>(v);  v = dpp_rot_max<0x4E>(v);
  return v;
}
template<int CTRL>
__device__ __forceinline__ void red_level7(float& s, float& sq, float* d) {
  s  = dpp_rot_add<CTRL>(s);
  sq = dpp_rot_add<CTRL>(sq);
#pragma unroll
  for (int j = 0; j < 5; j++) d[j] = dpp_rot_add<CTRL>(d[j]);
}
template<int JJ>
__device__ __forceinline__ float bcast16(float v) {
  int r = __builtin_amdgcn_ds_swizzle(__float_as_int(v), (JJ << 5) | 0x10);
  return __int_as_float(r);
}

union Frag8 { unsigned short us[8]; bf16x8 v; int4 i4; };

// ================= rnn_main: core blocks (0-63) + tail blocks (64-127) ======
// Core: R11 serial recurrence (unchanged pace); every 32 steps, after a
// vmcnt-drained barrier, tid0 publishes flags[blk*8+chunk] = chunk+1 with an
// agent-scope RELEASE store (L2 writeback -> h chunk cross-XCD visible).
// Tail block bt pairs with core block bt: polls flag (relaxed atomic +
// ACQUIRE fence = L2 invalidate), then LN1/proj (phase A) + 5-dim RNN2 scan
// (phase B) for that chunk. Tail runs CONCURRENTLY with the core on idle CUs.
// flags==nullptr: core-only mode (fallback pairs with rnn_tail_r11).
__global__ __launch_bounds__(512, 2)
void rnn_main(const int* __restrict__ x, const float* __restrict__ emb,
              const float* __restrict__ Wih1, const float* __restrict__ bih1,
              const float* __restrict__ Whh1, const float* __restrict__ bhh1,
              const float* __restrict__ g1, const float* __restrict__ be1,
              const float* __restrict__ Wih2, const float* __restrict__ bih2,
              const float* __restrict__ Whh2, const float* __restrict__ bhh2,
              const float* __restrict__ g2, const float* __restrict__ be2,
              unsigned short* __restrict__ hout, int* flags,
              float* __restrict__ out)
{
  __shared__ __align__(16) unsigned short h_bf[2][16 * 128];   // 8 KB
  __shared__ __align__(16) unsigned short e_bf[2][16 * 128];   // 8 KB
  __shared__ int x_tile[16 * 256];                             // 16 KB
  __shared__ __align__(16) float p_lds[8][2][32][8];           // 16 KB (tail)

  const int tid  = threadIdx.x;
  const int wave = tid >> 6;
  const int lane = tid & 63;
  const int l15  = lane & 15;
  const int q    = lane >> 4;

  if (blockIdx.x < 64) {
    // ========================= CORE ROLE =========================
    const int r0 = blockIdx.x * 16;
    for (int i = tid; i < 16 * 256; i += 512)
      x_tile[i] = x[(size_t)(r0 + (i >> 8)) * S_LEN + (i & 255)];
    for (int i = tid; i < 16 * 128; i += 512) h_bf[1][i] = 0;  // h_{-1} = 0

    const int n1 = wave * 16 + l15;
    const float bias1v = bih1[n1] + bhh1[n1];
    bf16x8 wh[4], wih[4];
#pragma unroll
    for (int kt = 0; kt < 4; kt++) {
      int k0 = kt * 32 + q * 8;
      Frag8 fh, fa;
#pragma unroll
      for (int j = 0; j < 8; j++) {
        fh.us[j] = f2bf_bits(Whh1[n1 * DIM + k0 + j]);
        fa.us[j] = f2bf_bits(Wih1[n1 * DIM + k0 + j]);
      }
      wh[kt] = fh.v; wih[kt] = fa.v;
    }

    const bool stage_role = (wave >= 4);
    float pf[2][8];
    const int gm   = (wave & 3) * 4 + q;   // staging row (waves 4-7)
    const int goct = l15;
    const int gdst = gm * 128 + ((goct ^ gm) & 15) * 8;
    __syncthreads();

    if (stage_role) {                    // stage e[0],e[1]; preload e[2],e[3]
      float ta[8], tb[8];
      { int xid = x_tile[gm * 256 + 0];
        const float* pe = emb + (size_t)xid * DIM + goct * 8;
#pragma unroll
        for (int j = 0; j < 8; j++) ta[j] = pe[j]; }
      { int xid = x_tile[gm * 256 + 1];
        const float* pe = emb + (size_t)xid * DIM + goct * 8;
#pragma unroll
        for (int j = 0; j < 8; j++) tb[j] = pe[j]; }
      { int xid = x_tile[gm * 256 + 2];
        const float* pe = emb + (size_t)xid * DIM + goct * 8;
#pragma unroll
        for (int j = 0; j < 8; j++) pf[0][j] = pe[j]; }
      { int xid = x_tile[gm * 256 + 3];
        const float* pe = emb + (size_t)xid * DIM + goct * 8;
#pragma unroll
        for (int j = 0; j < 8; j++) pf[1][j] = pe[j]; }
      Frag8 pa, pb;
#pragma unroll
      for (int j = 0; j < 8; j++) { pa.us[j] = f2bf_bits(ta[j]); pb.us[j] = f2bf_bits(tb[j]); }
      *(int4*)&e_bf[0][gdst] = pa.i4;
      *(int4*)&e_bf[1][gdst] = pb.i4;
    }
    __syncthreads();

    f32x4 xpacc = {bias1v, bias1v, bias1v, bias1v};
#pragma unroll
    for (int kt = 0; kt < 4; kt++) {
      int sw = (((kt * 4 + q) ^ l15) & 15) * 8;
      bf16x8 ae = *(const bf16x8*)&e_bf[0][l15 * 128 + sw];
      xpacc = __builtin_amdgcn_mfma_f32_16x16x32_bf16(ae, wih[kt], xpacc, 0, 0, 0);
    }
    asm volatile("s_waitcnt lgkmcnt(0)\n\ts_barrier" ::: "memory");

#pragma unroll 2
    for (int t = 0; t < S_LEN; t++) {
      // ---- serial core: acc seeded with xpacc, ONE depth-4 chain ----
      f32x4 acc = xpacc;
      {
        const int rb = (t + 1) & 1;      // h_{t-1}
#pragma unroll
        for (int kt = 0; kt < 4; kt++) {
          int sw = (((kt * 4 + q) ^ l15) & 15) * 8;
          bf16x8 ahf = *(const bf16x8*)&h_bf[rb][l15 * 128 + sw];
          acc = __builtin_amdgcn_mfma_f32_16x16x32_bf16(ahf, wh[kt], acc, 0, 0, 0);
        }
        const int wb = t & 1;
        const int oct = n1 >> 3;
#pragma unroll
        for (int r = 0; r < 4; r++) {    // D-layout: row = q*4 + r, col = l15
          int row = q * 4 + r;
          unsigned short us = (unsigned short)f2bf_rhu(tanh_fast(acc[r]));
          h_bf[wb][row * 128 + ((oct ^ row) & 15) * 8 + (n1 & 7)] = us;
          hout[((size_t)(r0 + row) * S_LEN + t) * DIM + n1] = us;  // off-chain
        }
      }

      if (t + 1 < S_LEN) {               // e_{t+1}@Wih into regs (off-chain)
        f32x4 a = {bias1v, bias1v, bias1v, bias1v};
#pragma unroll
        for (int kt = 0; kt < 4; kt++) {
          int sw = (((kt * 4 + q) ^ l15) & 15) * 8;
          bf16x8 ae = *(const bf16x8*)&e_bf[(t + 1) & 1][l15 * 128 + sw];
          a = __builtin_amdgcn_mfma_f32_16x16x32_bf16(ae, wih[kt], a, 0, 0, 0);
        }
        xpacc = a;
      }

      if (stage_role) {
        if (t + 2 < S_LEN) {             // stage e[t+2] (gathered at t-2)
          int4 pk;
          pk.x = pack_rhu(pf[t & 1][0], pf[t & 1][1]);
          pk.y = pack_rhu(pf[t & 1][2], pf[t & 1][3]);
          pk.z = pack_rhu(pf[t & 1][4], pf[t & 1][5]);
          pk.w = pack_rhu(pf[t & 1][6], pf[t & 1][7]);
          *(int4*)&e_bf[t & 1][gdst] = pk;
        }
        if (t + 4 < S_LEN) {             // issue gather e[t+4] (2-step cover)
          int xid = x_tile[gm * 256 + t + 4];
          const float* pe = emb + (size_t)xid * DIM + goct * 8;
#pragma unroll
          for (int j = 0; j < 8; j++) pf[t & 1][j] = pe[j];
        }
      }
      // chunk boundary: drain this wave's h stores before the barrier so the
      // post-barrier flag publish covers the whole block's chunk.
      if (flags != nullptr && (t & 31) == 31)
        asm volatile("s_waitcnt vmcnt(0)" ::: "memory");
      asm volatile("s_waitcnt lgkmcnt(0)\n\ts_barrier" ::: "memory");
      if (flags != nullptr && (t & 31) == 31 && tid == 0)
        __hip_atomic_store(&flags[blockIdx.x * 8 + (t >> 5)], (t >> 5) + 1,
                           __ATOMIC_RELEASE, __HIP_MEMORY_SCOPE_AGENT);
    }
  } else {
    // ========================= TAIL ROLE =========================
    const int bt = blockIdx.x - 64;      // paired core block
    float w2g[5][8], Gs[5], Bs[5], wrow[5];
#pragma unroll
    for (int j = 0; j < 8; j++) {
      int c = l15 * 8 + j;               // plain row-major channels
      float gc = g1[c];
#pragma unroll
      for (int jj = 0; jj < 5; jj++) w2g[jj][j] = Wih2[jj * DIM + c] * gc;
    }
#pragma unroll
    for (int jj = 0; jj < 5; jj++) { Gs[jj] = 0.f; Bs[jj] = 0.f; }
    for (int c = 0; c < DIM; c++) {
      float gc = g1[c], bc = be1[c];
#pragma unroll
      for (int jj = 0; jj < 5; jj++) {
        float w = Wih2[jj * DIM + c];
        Gs[jj] += w * gc; Bs[jj] += w * bc;
      }
    }
    const float validf = (l15 < 5) ? 1.f : 0.f;
    float t2_l = 0.f, g2_l = 0.f, be2_l = 0.f;
    if (l15 < 5) {
      t2_l = bih2[l15] + bhh2[l15];
      g2_l = g2[l15]; be2_l = be2[l15];
#pragma unroll
      for (int jj = 0; jj < 5; jj++) wrow[jj] = Whh2[l15 * 5 + jj];
    } else {
#pragma unroll
      for (int jj = 0; jj < 5; jj++) wrow[jj] = 0.f;
    }
    float h2rep[5] = {0, 0, 0, 0, 0}, pool_l = 0.f;
    const int row_l = 2 * wave + (q & 1);          // this group's row
    const unsigned short* hb =
        hout + (size_t)(bt * 16 + row_l) * S_LEN * DIM;
    const int idx = (l15 < 5) ? l15 : 0;

    for (int c8 = 0; c8 < 8; c8++) {
      if (tid == 0) {                    // poisoned flag is negative: waits
        while (__hip_atomic_load(&flags[bt * 8 + c8], __ATOMIC_RELAXED,
                                 __HIP_MEMORY_SCOPE_AGENT) < c8 + 1)
          __builtin_amdgcn_s_sleep(2);
      }
      __syncthreads();
      __builtin_amdgcn_fence(__ATOMIC_ACQUIRE, "agent");   // reader-side inv
      // phase A: LN1+proj for this chunk (2 rows x 32 t over 4 groups)
      for (int tt = 0; tt < 16; tt++) {
        int toff = tt * 2 + (q >> 1);
        uint4 cur = *(const uint4*)(hb + (size_t)(c8 * 32 + toff) * DIM + l15 * 8);
        float hv[8];
        hv[0] = __uint_as_float(cur.x << 16); hv[1] = __uint_as_float(cur.x & 0xffff0000u);
        hv[2] = __uint_as_float(cur.y << 16); hv[3] = __uint_as_float(cur.y & 0xffff0000u);
        hv[4] = __uint_as_float(cur.z << 16); hv[5] = __uint_as_float(cur.z & 0xffff0000u);
        hv[6] = __uint_as_float(cur.w << 16); hv[7] = __uint_as_float(cur.w & 0xffff0000u);
        float s = 0.f, sq = 0.f, d[5] = {0, 0, 0, 0, 0};
#pragma unroll
        for (int j = 0; j < 8; j++) {
          float v = hv[j];
          s += v; sq += v * v;
#pragma unroll
          for (int jj = 0; jj < 5; jj++) d[jj] = fmaf(w2g[jj][j], v, d[jj]);
        }
        red_level7<0x124>(s, sq, d);
        red_level7<0x128>(s, sq, d);
        red_level7<0x39>(s, sq, d);
        red_level7<0x4E>(s, sq, d);
        float mean = s * (1.f / 128.f);
        float var  = sq * (1.f / 128.f) - mean * mean;
        float rstd = rsqrtf(var + EPSL);
        float p[5];
#pragma unroll
        for (int jj = 0; jj < 5; jj++)
          p[jj] = rstd * (d[jj] - mean * Gs[jj]) + Bs[jj];
        float psel = (l15 == 0) ? p[0] : (l15 == 1) ? p[1] :
                     (l15 == 2) ? p[2] : (l15 == 3) ? p[3] : p[4];
        if (l15 < 5) p_lds[wave][q & 1][toff][l15] = psel;
      }
      asm volatile("s_waitcnt lgkmcnt(0)" ::: "memory");   // wave-local
      // phase B: 32 serial RNN2/LN2/pool steps (group-local, 1 tanh/step)
      for (int s = 0; s < 32; s++) {
        float pv = p_lds[wave][q & 1][s][idx];
        float a = pv + t2_l;
#pragma unroll
        for (int jj = 0; jj < 5; jj++) a = fmaf(wrow[jj], h2rep[jj], a);
        float xn = tanh_fast(a);
        float s2 = dpp_sum16(xn * validf) * 0.2f;
        float dd = xn - s2;
        float v2 = dpp_sum16(dd * dd * validf) * 0.2f;
        float r2 = rsqrtf(v2 + EPSL);
        pool_l += dd * r2 * g2_l + be2_l;
        h2rep[0] = bcast16<0>(xn); h2rep[1] = bcast16<1>(xn);
        h2rep[2] = bcast16<2>(xn); h2rep[3] = bcast16<3>(xn);
        h2rep[4] = bcast16<4>(xn);
      }
    }
    float lg = pool_l * (1.f / 256.f);
    float mx = dpp_max16((l15 < 5) ? lg : -3.0e38f);
    float e  = (l15 < 5) ? __expf(lg - mx) : 0.f;
    float sm = dpp_sum16(e);
    if (q < 2 && l15 < 5)
      out[(size_t)(bt * 16 + row_l) * 5 + l15] = e / sm;
  }
}

// ============ rnn_tail_r11: fallback tail (R11, interleaved) ================
__global__ __launch_bounds__(256, 2)
void rnn_tail_r11(const unsigned short* __restrict__ hall,
                  const float* __restrict__ g1,  const float* __restrict__ be1,
                  const float* __restrict__ Wih2, const float* __restrict__ bih2,
                  const float* __restrict__ Whh2, const float* __restrict__ bhh2,
                  const float* __restrict__ g2,  const float* __restrict__ be2,
                  float* __restrict__ out)
{
  __shared__ float p_lds[4][4][8];
  const int tid  = threadIdx.x;
  const int wave = tid >> 6;
  const int lane = tid & 63;
  const int l15  = lane & 15;
  const int q    = lane >> 4;
  const int b    = blockIdx.x * 4 + wave;

  float w2g[5][8], Gs[5], Bs[5], wrow[5];
#pragma unroll
  for (int j = 0; j < 8; j++) {
    int c = l15 * 8 + j;
    float gc = g1[c];
#pragma unroll
    for (int jj = 0; jj < 5; jj++) w2g[jj][j] = Wih2[jj * DIM + c] * gc;
  }
#pragma unroll
  for (int jj = 0; jj < 5; jj++) { Gs[jj] = 0.f; Bs[jj] = 0.f; }
  for (int c = 0; c < DIM; c++) {
    float gc = g1[c], bc = be1[c];
#pragma unroll
    for (int jj = 0; jj < 5; jj++) {
      float w = Wih2[jj * DIM + c];
      Gs[jj] += w * gc; Bs[jj] += w * bc;
    }
  }
  const float validf = (l15 < 5) ? 1.f : 0.f;
  float t2_l = 0.f, g2_l = 0.f, be2_l = 0.f;
  if (l15 < 5) {
    t2_l = bih2[l15] + bhh2[l15];
    g2_l = g2[l15]; be2_l = be2[l15];
#pragma unroll
    for (int jj = 0; jj < 5; jj++) wrow[jj] = Whh2[l15 * 5 + jj];
  } else {
#pragma unroll
    for (int jj = 0; jj < 5; jj++) wrow[jj] = 0.f;
  }
  float h2rep[5];
#pragma unroll
  for (int jj = 0; jj < 5; jj++) h2rep[jj] = 0.f;
  float pool_l = 0.f;

  const unsigned short* hb = hall + (size_t)b * S_LEN * DIM;
  uint4 hpre = *(const uint4*)(hb + (size_t)q * DIM + l15 * 8);

  for (int t0 = 0; t0 < S_LEN; t0 += 4) {
    uint4 cur = hpre;
    if (t0 + 4 < S_LEN)
      hpre = *(const uint4*)(hb + (size_t)(t0 + 4 + q) * DIM + l15 * 8);
    float hv[8];
    hv[0] = __uint_as_float(cur.x << 16); hv[1] = __uint_as_float(cur.x & 0xffff0000u);
    hv[2] = __uint_as_float(cur.y << 16); hv[3] = __uint_as_float(cur.y & 0xffff0000u);
    hv[4] = __uint_as_float(cur.z << 16); hv[5] = __uint_as_float(cur.z & 0xffff0000u);
    hv[6] = __uint_as_float(cur.w << 16); hv[7] = __uint_as_float(cur.w & 0xffff0000u);
    float s = 0.f, sq = 0.f, d[5] = {0, 0, 0, 0, 0};
#pragma unroll
    for (int j = 0; j < 8; j++) {
      float v = hv[j];
      s += v; sq += v * v;
#pragma unroll
      for (int jj = 0; jj < 5; jj++) d[jj] = fmaf(w2g[jj][j], v, d[jj]);
    }
    red_level7<0x124>(s, sq, d);
    red_level7<0x128>(s, sq, d);
    red_level7<0x39>(s, sq, d);
    red_level7<0x4E>(s, sq, d);
    float mean = s * (1.f / 128.f);
    float var  = sq * (1.f / 128.f) - mean * mean;
    float rstd = rsqrtf(var + EPSL);
    float p[5];
#pragma unroll
    for (int jj = 0; jj < 5; jj++)
      p[jj] = rstd * (d[jj] - mean * Gs[jj]) + Bs[jj];
    float psel = (l15 == 0) ? p[0] : (l15 == 1) ? p[1] :
                 (l15 == 2) ? p[2] : (l15 == 3) ? p[3] : p[4];
    if (l15 < 5) p_lds[wave][q][l15] = psel;
    asm volatile("s_waitcnt lgkmcnt(0)" ::: "memory");
    const int idx = (l15 < 5) ? l15 : 0;
#pragma unroll
    for (int g = 0; g < 4; g++) {
      float pv = p_lds[wave][g][idx];
      float a = pv + t2_l;
#pragma unroll
      for (int jj = 0; jj < 5; jj++) a = fmaf(wrow[jj], h2rep[jj], a);
      float xn = tanh_fast(a);
      float s2 = dpp_sum16(xn * validf) * 0.2f;
      float dd = xn - s2;
      float v2 = dpp_sum16(dd * dd * validf) * 0.2f;
      float r2 = rsqrtf(v2 + EPSL);
      pool_l += dd * r2 * g2_l + be2_l;
      h2rep[0] = bcast16<0>(xn); h2rep[1] = bcast16<1>(xn);
      h2rep[2] = bcast16<2>(xn); h2rep[3] = bcast16<3>(xn);
      h2rep[4] = bcast16<4>(xn);
    }
  }

  float lg = pool_l * (1.f / 256.f);
  float mx = dpp_max16((l15 < 5) ? lg : -3.0e38f);
  float e  = (l15 < 5) ? __expf(lg - mx) : 0.f;
  float sm = dpp_sum16(e);
  if (q == 0 && l15 < 5) out[(size_t)b * 5 + l15] = e / sm;
}

extern "C" void kernel_launch(void* const* d_in, const int* in_sizes, int n_in,
                              void* d_out, int out_size, void* d_ws, size_t ws_size,
                              hipStream_t stream) {
  (void)in_sizes; (void)n_in; (void)out_size;
  const int*   x    = (const int*)  d_in[0];
  const float* emb  = (const float*)d_in[1];
  const float* Wih1 = (const float*)d_in[2];
  const float* bih1 = (const float*)d_in[3];
  const float* Whh1 = (const float*)d_in[4];
  const float* bhh1 = (const float*)d_in[5];
  const float* g1   = (const float*)d_in[6];
  const float* be1  = (const float*)d_in[7];
  const float* Wih2 = (const float*)d_in[8];
  const float* bih2 = (const float*)d_in[9];
  const float* Whh2 = (const float*)d_in[10];
  const float* bhh2 = (const float*)d_in[11];
  const float* g2   = (const float*)d_in[12];
  const float* be2  = (const float*)d_in[13];
  float* out = (float*)d_out;

  const size_t HBYTES = (size_t)1024 * S_LEN * DIM * 2;   // 64 MiB bf16 h
  const size_t FBYTES = 64 * 8 * sizeof(int);             // chunk flags
  unsigned short* hws = (unsigned short*)d_ws;

  if (ws_size >= HBYTES + 4096) {
    int* flags = (int*)((char*)d_ws + HBYTES);
    rnn_main<<<dim3(128), dim3(512), 0, stream>>>(
        x, emb, Wih1, bih1, Whh1, bhh1, g1, be1,
        Wih2, bih2, Whh2, bhh2, g2, be2, hws, flags, out);
    (void)FBYTES;
  } else {
    // fallback: R11 two-kernel path (core-only mode, flags = nullptr)
    rnn_main<<<dim3(64), dim3(512), 0, stream>>>(
        x, emb, Wih1, bih1, Whh1, bhh1, g1, be1,
        Wih2, bih2, Whh2, bhh2, g2, be2, hws, nullptr, out);
    rnn_tail_r11<<<dim3(256), dim3(256), 0, stream>>>(
        hws, g1, be1, Wih2, bih2, Whh2, bhh2, g2, be2, out);
  }
}